// Round 1
// baseline (623.083 us; speedup 1.0000x reference)
//
#include <hip/hip_runtime.h>

// GumbelCodebook: y = one_hot(argmax(logits+gumbel)), z = codebook[argmax]
// Shapes: logits/gumbel [8,4096,2048] f32, codebook [2048,256] f32
// Outputs concatenated in d_out: z [8,4096,256] then y [8,4096,2048], f32.
//
// v2: one WAVE (64 lanes) per token instead of one block per token.
//  - 64 lanes x 32 codes = 2048: argmax is a pure wave butterfly reduce
//    (__shfl_xor), so NO LDS, NO __syncthreads, no serial tid==0 section.
//  - 8 float4 pairs in flight per lane (2x the MLP of v1).
//  - __launch_bounds__(256, 8): cap VGPRs at ~64 so 8 blocks/CU stay resident.

#define NUM_CODES 2048
#define CODE_DIM  256
#define BLOCK     256
#define WAVES_PER_BLOCK (BLOCK / 64)
#define VECS 8   // 8 x float4 = 32 codes/lane * 64 lanes = 2048

__global__ __launch_bounds__(BLOCK, 8) void gumbel_codebook_kernel(
    const float* __restrict__ logits,
    const float* __restrict__ gumbel,
    const float* __restrict__ codebook,
    float* __restrict__ z_out,   // [tokens, CODE_DIM]
    float* __restrict__ y_out,   // [tokens, NUM_CODES]
    int tokens)
{
    const int lane = threadIdx.x & 63;
    const int wave = threadIdx.x >> 6;
    const int token = blockIdx.x * WAVES_PER_BLOCK + wave;
    if (token >= tokens) return;

    const size_t row_off = (size_t)token * NUM_CODES;
    const float4* lrow = (const float4*)(logits + row_off);
    const float4* grow = (const float4*)(gumbel + row_off);

    // --- per-lane argmax over 32 codes. For fixed lane, index (c*64+lane)*4
    // increases with c, so strict '>' keeps the first (lowest-index) max,
    // matching jnp.argmax tie-break within the lane. ---
    float best = -INFINITY;
    int bestIdx = NUM_CODES;  // sentinel
#pragma unroll
    for (int c = 0; c < VECS; ++c) {
        const int vec = c * 64 + lane;          // contiguous 1KB per instr
        const int base = vec * 4;
        float4 l = lrow[vec];
        float4 g = grow[vec];
        float s0 = l.x + g.x;
        float s1 = l.y + g.y;
        float s2 = l.z + g.z;
        float s3 = l.w + g.w;
        if (s0 > best) { best = s0; bestIdx = base + 0; }
        if (s1 > best) { best = s1; bestIdx = base + 1; }
        if (s2 > best) { best = s2; bestIdx = base + 2; }
        if (s3 > best) { best = s3; bestIdx = base + 3; }
    }

    // --- wave butterfly argmax: every lane ends with the global winner;
    // lower index wins ties (global first-occurrence semantics). ---
#pragma unroll
    for (int m = 1; m < 64; m <<= 1) {
        float ob = __shfl_xor(best, m, 64);
        int   oi = __shfl_xor(bestIdx, m, 64);
        if (ob > best || (ob == best && oi < bestIdx)) { best = ob; bestIdx = oi; }
    }
    const int amax = bestIdx;

    // --- write y (one-hot). Compare-per-element: 4 cndmask, no dynamic
    // indexing of a local array (avoids scratch). ---
    float4* yrow = (float4*)(y_out + row_off);
#pragma unroll
    for (int c = 0; c < VECS; ++c) {
        const int vec = c * 64 + lane;
        const int base = vec * 4;
        float4 out;
        out.x = (amax == base + 0) ? 1.0f : 0.0f;
        out.y = (amax == base + 1) ? 1.0f : 0.0f;
        out.z = (amax == base + 2) ? 1.0f : 0.0f;
        out.w = (amax == base + 3) ? 1.0f : 0.0f;
        yrow[vec] = out;
    }

    // --- write z = codebook[amax]: one float4 per lane (64*16B = 1KB row).
    // Codebook is 2MB -> L2-resident after warmup. ---
    const float4* crow = (const float4*)(codebook + (size_t)amax * CODE_DIM);
    float4* zrow = (float4*)(z_out + (size_t)token * CODE_DIM);
    zrow[lane] = crow[lane];
}

extern "C" void kernel_launch(void* const* d_in, const int* in_sizes, int n_in,
                              void* d_out, int out_size, void* d_ws, size_t ws_size,
                              hipStream_t stream) {
    const float* logits   = (const float*)d_in[0];
    const float* gumbel   = (const float*)d_in[1];
    const float* codebook = (const float*)d_in[2];

    const int tokens = in_sizes[0] / NUM_CODES;  // 8*4096 = 32768

    float* z_out = (float*)d_out;                               // [tokens, 256]
    float* y_out = (float*)d_out + (size_t)tokens * CODE_DIM;   // [tokens, 2048]

    const int grid = (tokens + WAVES_PER_BLOCK - 1) / WAVES_PER_BLOCK;
    gumbel_codebook_kernel<<<grid, BLOCK, 0, stream>>>(
        logits, gumbel, codebook, z_out, y_out, tokens);
}